// Round 1
// baseline (429.038 us; speedup 1.0000x reference)
//
#include <hip/hip_runtime.h>
#include <math.h>

// Transformer block: pre-LN attn + residual, pre-LN MLP(GELU) + residual.
// B=2,S=2048,D=1024,H=16,hd=64,F=4096. fp32 in/out, bf16 MFMA compute.

typedef __attribute__((ext_vector_type(8))) short s8v;   // 8 x bf16 (16B)
typedef __attribute__((ext_vector_type(4))) short s4v;   // 4 x bf16 (8B)
typedef __attribute__((ext_vector_type(4))) float f4v;   // MFMA acc

#define M_ROWS 4096
#define DM 1024
#define FF 4096

__device__ inline short f2bf(float f) {
  unsigned u = __builtin_bit_cast(unsigned, f);
  u += 0x7fff + ((u >> 16) & 1);          // round-to-nearest-even
  return (short)(u >> 16);
}

// ---------------- weight transpose+convert: W[K][N] f32 -> Wt[N][K] bf16 ----
__global__ void wt_kernel(const float* __restrict__ W, short* __restrict__ Wt,
                          int K, int N) {
  __shared__ float tile[32][33];
  int tx = threadIdx.x, ty = threadIdx.y;            // (32,8)
  int n0 = blockIdx.x * 32, k0 = blockIdx.y * 32;
#pragma unroll
  for (int i = 0; i < 4; ++i)
    tile[ty + 8 * i][tx] = W[(size_t)(k0 + ty + 8 * i) * N + n0 + tx];
  __syncthreads();
#pragma unroll
  for (int i = 0; i < 4; ++i)
    Wt[(size_t)(n0 + ty + 8 * i) * K + k0 + tx] = f2bf(tile[tx][ty + 8 * i]);
}

// ---------------- LayerNorm: f32 [rows][1024] -> bf16 ----------------------
__global__ __launch_bounds__(256) void ln_kernel(const float* __restrict__ x,
                                                 const float* __restrict__ g,
                                                 const float* __restrict__ b,
                                                 short* __restrict__ out) {
  int row = blockIdx.x, tid = threadIdx.x;
  const float4* xr = (const float4*)(x + (size_t)row * DM);
  float4 v = xr[tid];                                 // 256 threads * 4 = 1024
  float s = v.x + v.y + v.z + v.w;
  float q = v.x * v.x + v.y * v.y + v.z * v.z + v.w * v.w;
#pragma unroll
  for (int off = 32; off; off >>= 1) {
    s += __shfl_down(s, off);
    q += __shfl_down(q, off);
  }
  __shared__ float red[8];
  if ((tid & 63) == 0) { red[tid >> 6] = s; red[4 + (tid >> 6)] = q; }
  __syncthreads();
  if (tid == 0) {
    float S = red[0] + red[1] + red[2] + red[3];
    float Q = red[4] + red[5] + red[6] + red[7];
    float mean = S * (1.0f / DM);
    float var = Q * (1.0f / DM) - mean * mean;
    red[0] = mean;
    red[1] = rsqrtf(var + 1e-5f);
  }
  __syncthreads();
  float mean = red[0], rstd = red[1];
  float4 gv = ((const float4*)g)[tid], bv = ((const float4*)b)[tid];
  s4v o;
  o[0] = f2bf((v.x - mean) * rstd * gv.x + bv.x);
  o[1] = f2bf((v.y - mean) * rstd * gv.y + bv.y);
  o[2] = f2bf((v.z - mean) * rstd * gv.z + bv.z);
  o[3] = f2bf((v.w - mean) * rstd * gv.w + bv.w);
  *(s4v*)&out[(size_t)row * DM + tid * 4] = o;
}

// ---------------- GEMM: C[M,N] = A[M,K](bf16) @ Bt[N,K]^T(bf16) ------------
// EPI 0: C bf16 = acc
// EPI 1: C f32  = acc + bias[n] + res[m,n]
// EPI 2: C bf16 = gelu(acc + bias[n])
#define BKT 64
#define LDT 72  // padded LDS stride (elems); 144B rows -> <=2-way conflicts

template <int EPI>
__global__ __launch_bounds__(256, 2) void gemm_kernel(
    const short* __restrict__ A, const short* __restrict__ Bt,
    const float* __restrict__ bias, const float* __restrict__ res,
    void* __restrict__ Cout, int M, int N, int K) {
  __shared__ short As[128 * LDT];
  __shared__ short Bs[128 * LDT];
  int tid = threadIdx.x, lane = tid & 63, wave = tid >> 6;
  int wr = wave >> 1, wc = wave & 1;
  int l16 = lane & 15, lhi = lane >> 4;
  int row0 = blockIdx.y * 128, col0 = blockIdx.x * 128;

  const f4v fzero = {0.f, 0.f, 0.f, 0.f};
  f4v acc[4][4];
#pragma unroll
  for (int m = 0; m < 4; ++m)
#pragma unroll
    for (int n = 0; n < 4; ++n) acc[m][n] = fzero;

  for (int k0 = 0; k0 < K; k0 += BKT) {
    __syncthreads();
#pragma unroll
    for (int i = 0; i < 4; ++i) {                 // stage 128x64 A and B tiles
      int c = tid + 256 * i;                      // 1024 chunks of 8 elems
      int r = c >> 3, col8 = (c & 7) * 8;
      *(s8v*)&As[r * LDT + col8] =
          *(const s8v*)&A[(size_t)(row0 + r) * K + k0 + col8];
      *(s8v*)&Bs[r * LDT + col8] =
          *(const s8v*)&Bt[(size_t)(col0 + r) * K + k0 + col8];
    }
    __syncthreads();
#pragma unroll
    for (int kk = 0; kk < 2; ++kk) {
      s8v af[4], bfr[4];
#pragma unroll
      for (int m = 0; m < 4; ++m)
        af[m] = *(const s8v*)&As[(wr * 64 + m * 16 + l16) * LDT + kk * 32 + lhi * 8];
#pragma unroll
      for (int n = 0; n < 4; ++n)
        bfr[n] = *(const s8v*)&Bs[(wc * 64 + n * 16 + l16) * LDT + kk * 32 + lhi * 8];
#pragma unroll
      for (int m = 0; m < 4; ++m)
#pragma unroll
        for (int n = 0; n < 4; ++n)
          acc[m][n] = __builtin_amdgcn_mfma_f32_16x16x32_bf16(af[m], bfr[n],
                                                              acc[m][n], 0, 0, 0);
    }
  }
  // epilogue: D layout col=lane&15, row=(lane>>4)*4+reg
#pragma unroll
  for (int m = 0; m < 4; ++m)
#pragma unroll
    for (int n = 0; n < 4; ++n)
#pragma unroll
      for (int r = 0; r < 4; ++r) {
        int row = row0 + wr * 64 + m * 16 + lhi * 4 + r;
        int col = col0 + wc * 64 + n * 16 + l16;
        size_t idx = (size_t)row * N + col;
        float v = acc[m][n][r];
        if (EPI == 0) {
          ((short*)Cout)[idx] = f2bf(v);
        } else if (EPI == 1) {
          ((float*)Cout)[idx] = v + bias[col] + res[idx];
        } else {
          float t = v + bias[col];
          t = 0.5f * t * (1.0f + erff(t * 0.70710678118f));
          ((short*)Cout)[idx] = f2bf(t);
        }
      }
}

// ---------------- Flash attention: q,k,v bf16 [B*S][H*hd] -> o bf16 --------
// grid: (S/64, B*H). 4 waves, wave w handles q rows [w*16, w*16+16).
__global__ __launch_bounds__(256, 2) void attn_kernel(const short* __restrict__ q,
                                                      const short* __restrict__ k,
                                                      const short* __restrict__ v,
                                                      short* __restrict__ o) {
  __shared__ short Ks[64 * 64];       // [key][d]  swizzled
  __shared__ short Vs[64 * 64];       // [d][key]  transposed + swizzled
  __shared__ short Ps[4 * 16 * 64];   // per-wave P[qrow][key] swizzled
  int tid = threadIdx.x, lane = tid & 63, w = tid >> 6;
  int l16 = lane & 15, lhi = lane >> 4;
  int qb = blockIdx.x * 64;
  int bh = blockIdx.y;
  int b = bh >> 4, h = bh & 15;
  const size_t base = (size_t)b * 2048 * 1024 + (size_t)h * 64;

  // Q fragments held in registers for the whole kernel (A: row=lane%16, k-contig)
  s8v qf[2];
  int qrow = qb + w * 16 + l16;
#pragma unroll
  for (int kk = 0; kk < 2; ++kk)
    qf[kk] = *(const s8v*)&q[base + (size_t)qrow * 1024 + kk * 32 + lhi * 8];

  const f4v fzero = {0.f, 0.f, 0.f, 0.f};
  f4v oacc[4];
  float mreg[4], lsum[4];
#pragma unroll
  for (int r = 0; r < 4; ++r) { oacc[r] = fzero; mreg[r] = -1e30f; lsum[r] = 0.f; }

  for (int kt = 0; kt < 2048; kt += 64) {
    __syncthreads();
    // stage K (row-major, XOR swizzle) and V (transposed, XOR swizzle)
#pragma unroll
    for (int i = 0; i < 2; ++i) {
      int c = tid + 256 * i;            // 512 chunks of 8
      int r = c >> 3, col8 = (c & 7) * 8;
      s8v kv = *(const s8v*)&k[base + (size_t)(kt + r) * 1024 + col8];
      *(s8v*)&Ks[r * 64 + (col8 ^ ((r & 7) << 3))] = kv;
      s8v vv = *(const s8v*)&v[base + (size_t)(kt + r) * 1024 + col8];
#pragma unroll
      for (int j = 0; j < 8; ++j) {
        int d = col8 + j;
        Vs[d * 64 + (r ^ ((d & 7) << 3))] = vv[j];
      }
    }
    __syncthreads();

    // S = (Q @ K^T) * 0.125 for 16 q-rows x 64 keys per wave
    f4v s[4];
#pragma unroll
    for (int nb = 0; nb < 4; ++nb) s[nb] = fzero;
#pragma unroll
    for (int kk = 0; kk < 2; ++kk) {
#pragma unroll
      for (int nb = 0; nb < 4; ++nb) {
        int key = nb * 16 + l16;
        int col = kk * 32 + lhi * 8;
        s8v kf = *(const s8v*)&Ks[key * 64 + (col ^ ((key & 7) << 3))];
        s[nb] = __builtin_amdgcn_mfma_f32_16x16x32_bf16(qf[kk], kf, s[nb], 0, 0, 0);
      }
    }

    // online softmax (row = lhi*4 + r; 16-lane groups share rows)
    float pp[4][4], sc_[4];
#pragma unroll
    for (int r = 0; r < 4; ++r) {
      float mt = fmaxf(fmaxf(s[0][r], s[1][r]), fmaxf(s[2][r], s[3][r])) * 0.125f;
#pragma unroll
      for (int off = 1; off < 16; off <<= 1) mt = fmaxf(mt, __shfl_xor(mt, off));
      float newm = fmaxf(mreg[r], mt);
      float sc = __expf(mreg[r] - newm);
      mreg[r] = newm;
      float rowsum = 0.f;
#pragma unroll
      for (int nb = 0; nb < 4; ++nb) {
        float pvv = __expf(s[nb][r] * 0.125f - newm);
        pp[nb][r] = pvv;
        rowsum += pvv;
      }
#pragma unroll
      for (int off = 1; off < 16; off <<= 1) rowsum += __shfl_xor(rowsum, off);
      lsum[r] = lsum[r] * sc + rowsum;
      sc_[r] = sc;
    }
#pragma unroll
    for (int nb = 0; nb < 4; ++nb)
#pragma unroll
      for (int r = 0; r < 4; ++r) oacc[nb][r] *= sc_[r];

    // write P (bf16) to per-wave LDS region in A-fragment layout
#pragma unroll
    for (int r = 0; r < 4; ++r) {
      int prow = lhi * 4 + r;
#pragma unroll
      for (int nb = 0; nb < 4; ++nb) {
        int key = nb * 16 + l16;
        Ps[w * 1024 + prow * 64 + (key ^ ((prow & 7) << 3))] = f2bf(pp[nb][r]);
      }
    }
    __syncthreads();

    // O += P @ V
#pragma unroll
    for (int kk2 = 0; kk2 < 2; ++kk2) {
      int keyc = kk2 * 32 + lhi * 8;
      s8v pf = *(const s8v*)&Ps[w * 1024 + l16 * 64 + (keyc ^ ((l16 & 7) << 3))];
#pragma unroll
      for (int nb = 0; nb < 4; ++nb) {
        int d = nb * 16 + l16;
        s8v vf = *(const s8v*)&Vs[d * 64 + (keyc ^ ((d & 7) << 3))];
        oacc[nb] = __builtin_amdgcn_mfma_f32_16x16x32_bf16(pf, vf, oacc[nb], 0, 0, 0);
      }
    }
  }

  // normalize + store
#pragma unroll
  for (int nb = 0; nb < 4; ++nb)
#pragma unroll
    for (int r = 0; r < 4; ++r) {
      float ov = oacc[nb][r] / lsum[r];
      int qr2 = qb + w * 16 + lhi * 4 + r;
      o[base + (size_t)qr2 * 1024 + nb * 16 + l16] = f2bf(ov);
    }
}

// ---------------------------------------------------------------------------
extern "C" void kernel_launch(void* const* d_in, const int* in_sizes, int n_in,
                              void* d_out, int out_size, void* d_ws, size_t ws_size,
                              hipStream_t stream) {
  (void)in_sizes; (void)n_in; (void)out_size; (void)ws_size;
  const float* x    = (const float*)d_in[0];
  const float* ln1g = (const float*)d_in[1];
  const float* ln1b = (const float*)d_in[2];
  const float* wq   = (const float*)d_in[3];
  const float* wk   = (const float*)d_in[4];
  const float* wv   = (const float*)d_in[5];
  const float* wo   = (const float*)d_in[6];
  const float* bo   = (const float*)d_in[7];
  const float* ln2g = (const float*)d_in[8];
  const float* ln2b = (const float*)d_in[9];
  const float* w1   = (const float*)d_in[10];
  const float* b1   = (const float*)d_in[11];
  const float* w2   = (const float*)d_in[12];
  const float* b2   = (const float*)d_in[13];
  float* out = (float*)d_out;

  char* ws = (char*)d_ws;
  const size_t MB = 1024 * 1024;
  // region A (32MB): h1,q,k,v; reused later as MLP intermediate (32MB)
  short* h1  = (short*)(ws);
  short* qb  = (short*)(ws + 8 * MB);
  short* kb  = (short*)(ws + 16 * MB);
  short* vb  = (short*)(ws + 24 * MB);
  short* mid = (short*)(ws);                 // after attention, region A is free
  // region B (8MB): attention out; reused as h2 after proj
  short* at  = (short*)(ws + 32 * MB);
  short* h2  = (short*)(ws + 32 * MB);
  // region C (16MB): x2 residual f32
  float* x2  = (float*)(ws + 40 * MB);
  // region D (24MB): bf16 transposed weights
  short* wqT = (short*)(ws + 56 * MB);
  short* wkT = (short*)(ws + 58 * MB);
  short* wvT = (short*)(ws + 60 * MB);
  short* woT = (short*)(ws + 62 * MB);
  short* w1T = (short*)(ws + 64 * MB);       // [4096][1024]
  short* w2T = (short*)(ws + 72 * MB);       // [1024][4096]

  dim3 tb(32, 8);
  wt_kernel<<<dim3(32, 32), tb, 0, stream>>>(wq, wqT, 1024, 1024);
  wt_kernel<<<dim3(32, 32), tb, 0, stream>>>(wk, wkT, 1024, 1024);
  wt_kernel<<<dim3(32, 32), tb, 0, stream>>>(wv, wvT, 1024, 1024);
  wt_kernel<<<dim3(32, 32), tb, 0, stream>>>(wo, woT, 1024, 1024);
  wt_kernel<<<dim3(128, 32), tb, 0, stream>>>(w1, w1T, 1024, 4096);
  wt_kernel<<<dim3(32, 128), tb, 0, stream>>>(w2, w2T, 4096, 1024);

  ln_kernel<<<M_ROWS, 256, 0, stream>>>(x, ln1g, ln1b, h1);

  gemm_kernel<0><<<dim3(8, 32), 256, 0, stream>>>(h1, wqT, nullptr, nullptr, qb, M_ROWS, DM, DM);
  gemm_kernel<0><<<dim3(8, 32), 256, 0, stream>>>(h1, wkT, nullptr, nullptr, kb, M_ROWS, DM, DM);
  gemm_kernel<0><<<dim3(8, 32), 256, 0, stream>>>(h1, wvT, nullptr, nullptr, vb, M_ROWS, DM, DM);

  attn_kernel<<<dim3(32, 32), 256, 0, stream>>>(qb, kb, vb, at);

  gemm_kernel<1><<<dim3(8, 32), 256, 0, stream>>>(at, woT, bo, x, x2, M_ROWS, DM, DM);

  ln_kernel<<<M_ROWS, 256, 0, stream>>>(x2, ln2g, ln2b, h2);

  gemm_kernel<2><<<dim3(32, 32), 256, 0, stream>>>(h2, w1T, b1, nullptr, mid, M_ROWS, FF, DM);

  gemm_kernel<1><<<dim3(8, 32), 256, 0, stream>>>(mid, w2T, b2, x2, out, M_ROWS, DM, FF);
}

// Round 3
// 375.940 us; speedup vs baseline: 1.1412x; 1.1412x over previous
//
#include <hip/hip_runtime.h>
#include <math.h>

// Transformer block: pre-LN attn + residual, pre-LN MLP(GELU) + residual.
// B=2,S=2048,D=1024,H=16,hd=64,F=4096. fp32 in/out, bf16 MFMA compute.

typedef __attribute__((ext_vector_type(8))) short s8v;   // 8 x bf16 (16B)
typedef __attribute__((ext_vector_type(4))) short s4v;   // 4 x bf16 (8B)
typedef __attribute__((ext_vector_type(4))) float f4v;   // MFMA acc

#define M_ROWS 4096
#define DM 1024
#define FF 4096
#define QKV_LD 3072   // fused qkv row stride

__device__ inline short f2bf(float f) {
  unsigned u = __builtin_bit_cast(unsigned, f);
  u += 0x7fff + ((u >> 16) & 1);          // round-to-nearest-even
  return (short)(u >> 16);
}

// async global->LDS, 16B per lane. dst must be wave-uniform base; HW writes
// base + lane*16. src is per-lane.
__device__ inline void gload_lds16(const void* g, void* lds) {
  __builtin_amdgcn_global_load_lds(
      (const __attribute__((address_space(1))) unsigned*)(uintptr_t)g,
      (__attribute__((address_space(3))) unsigned*)(unsigned)(uintptr_t)lds,
      16, 0, 0);
}

// hardware transpose read: returns 4 bf16 at byte offsets off+{0,32,64,96}
// (stride 16 elements) — m156 layout.
__device__ inline s4v ds_tr16(unsigned off) {
  s4v r;
  asm volatile("ds_read_b64_tr_b16 %0, %1" : "=v"(r) : "v"(off));
  return r;
}

__device__ inline s8v cat8(s4v a, s4v b) {
  return __builtin_shufflevector(a, b, 0, 1, 2, 3, 4, 5, 6, 7);
}

// ---------------- weight transpose+convert: W[K][N] f32 -> Wt[N][K] bf16 ----
__global__ void wt_kernel(const float* __restrict__ W, short* __restrict__ Wt,
                          int K, int N) {
  __shared__ float tile[32][33];
  int tx = threadIdx.x, ty = threadIdx.y;            // (32,8)
  int n0 = blockIdx.x * 32, k0 = blockIdx.y * 32;
#pragma unroll
  for (int i = 0; i < 4; ++i)
    tile[ty + 8 * i][tx] = W[(size_t)(k0 + ty + 8 * i) * N + n0 + tx];
  __syncthreads();
#pragma unroll
  for (int i = 0; i < 4; ++i)
    Wt[(size_t)(n0 + ty + 8 * i) * K + k0 + tx] = f2bf(tile[tx][ty + 8 * i]);
}

// ---------------- LayerNorm: f32 [rows][1024] -> bf16 ----------------------
__global__ __launch_bounds__(256) void ln_kernel(const float* __restrict__ x,
                                                 const float* __restrict__ g,
                                                 const float* __restrict__ b,
                                                 short* __restrict__ out) {
  int row = blockIdx.x, tid = threadIdx.x;
  const float4* xr = (const float4*)(x + (size_t)row * DM);
  float4 v = xr[tid];                                 // 256 threads * 4 = 1024
  float s = v.x + v.y + v.z + v.w;
  float q = v.x * v.x + v.y * v.y + v.z * v.z + v.w * v.w;
#pragma unroll
  for (int off = 32; off; off >>= 1) {
    s += __shfl_down(s, off);
    q += __shfl_down(q, off);
  }
  __shared__ float red[8];
  if ((tid & 63) == 0) { red[tid >> 6] = s; red[4 + (tid >> 6)] = q; }
  __syncthreads();
  if (tid == 0) {
    float S = red[0] + red[1] + red[2] + red[3];
    float Q = red[4] + red[5] + red[6] + red[7];
    float mean = S * (1.0f / DM);
    float var = Q * (1.0f / DM) - mean * mean;
    red[0] = mean;
    red[1] = rsqrtf(var + 1e-5f);
  }
  __syncthreads();
  float mean = red[0], rstd = red[1];
  float4 gv = ((const float4*)g)[tid], bv = ((const float4*)b)[tid];
  s4v o;
  o[0] = f2bf((v.x - mean) * rstd * gv.x + bv.x);
  o[1] = f2bf((v.y - mean) * rstd * gv.y + bv.y);
  o[2] = f2bf((v.z - mean) * rstd * gv.z + bv.z);
  o[3] = f2bf((v.w - mean) * rstd * gv.w + bv.w);
  *(s4v*)&out[(size_t)row * DM + tid * 4] = o;
}

// ---------------- GEMM (m97 structure): C = A[M,K] @ Bt[N,K]^T -------------
// linear [128][64] LDS tiles, global_load_lds width-16 staging.
// EPI 0: C bf16 = acc            (ldc = N)
// EPI 1: C f32  = acc + bias[n] + res[m,n]
// EPI 2: C bf16 = gelu(acc + bias[n])
template <int EPI>
__global__ __launch_bounds__(256) void gemm_kernel(
    const short* __restrict__ A, const short* __restrict__ Bt,
    const float* __restrict__ bias, const float* __restrict__ res,
    void* __restrict__ Cout, int M, int N, int K) {
  __shared__ short As[128 * 64];
  __shared__ short Bs[128 * 64];
  int tid = threadIdx.x, lane = tid & 63, wave = tid >> 6;
  int wr = wave >> 1, wc = wave & 1;
  int l16 = lane & 15, lhi = lane >> 4;
  int row0 = blockIdx.y * 128, col0 = blockIdx.x * 128;
  int lrow = lane >> 3, lcol8 = (lane & 7) * 8;     // staging lane coords

  const f4v fzero = {0.f, 0.f, 0.f, 0.f};
  f4v acc[4][4];
#pragma unroll
  for (int m = 0; m < 4; ++m)
#pragma unroll
    for (int n = 0; n < 4; ++n) acc[m][n] = fzero;

  for (int k0 = 0; k0 < K; k0 += 64) {
    __syncthreads();
#pragma unroll
    for (int i = 0; i < 4; ++i) {       // 16 chunks of 1024B per matrix
      int ch = wave * 4 + i;
      int row = ch * 8 + lrow;
      gload_lds16(&A[(size_t)(row0 + row) * K + k0 + lcol8], &As[ch * 512]);
      gload_lds16(&Bt[(size_t)(col0 + row) * K + k0 + lcol8], &Bs[ch * 512]);
    }
    __syncthreads();
#pragma unroll
    for (int kk = 0; kk < 2; ++kk) {
      s8v af[4], bfr[4];
#pragma unroll
      for (int m = 0; m < 4; ++m)
        af[m] = *(const s8v*)&As[(wr * 64 + m * 16 + l16) * 64 + kk * 32 + lhi * 8];
#pragma unroll
      for (int n = 0; n < 4; ++n)
        bfr[n] = *(const s8v*)&Bs[(wc * 64 + n * 16 + l16) * 64 + kk * 32 + lhi * 8];
#pragma unroll
      for (int m = 0; m < 4; ++m)
#pragma unroll
        for (int n = 0; n < 4; ++n)
          acc[m][n] = __builtin_amdgcn_mfma_f32_16x16x32_bf16(af[m], bfr[n],
                                                              acc[m][n], 0, 0, 0);
    }
  }
  // epilogue: D layout col=lane&15, row=(lane>>4)*4+reg
#pragma unroll
  for (int m = 0; m < 4; ++m)
#pragma unroll
    for (int n = 0; n < 4; ++n)
#pragma unroll
      for (int r = 0; r < 4; ++r) {
        int row = row0 + wr * 64 + m * 16 + lhi * 4 + r;
        int col = col0 + wc * 64 + n * 16 + l16;
        size_t idx = (size_t)row * N + col;
        float v = acc[m][n][r];
        if (EPI == 0) {
          ((short*)Cout)[idx] = f2bf(v);
        } else if (EPI == 1) {
          ((float*)Cout)[idx] = v + bias[col] + res[idx];
        } else {
          float t = v + bias[col];
          t = 0.5f * t * (1.0f + erff(t * 0.70710678118f));
          ((short*)Cout)[idx] = f2bf(t);
        }
      }
}

// ---------------- Flash attention ------------------------------------------
// q,k,v point into fused qkv buffer [4096][3072] (q=+0,k=+1024,v=+2048).
// grid: (S/64, B*H). 4 waves, wave w owns q rows [w*16, w*16+16).
// K staged row-major XOR-swizzled; V and P staged in tr-read subtile layout
// ([g2][half][jj][c]: elem addr = g2*128+half*64+jj*16+c holds X[key=g2*8+
// half*4+jj][c]).  All K/V staging via global_load_lds (swizzle on the
// global source address, LDS linear — rule 21).
__global__ __launch_bounds__(256) void attn_kernel(const short* __restrict__ q,
                                                   const short* __restrict__ k,
                                                   const short* __restrict__ v,
                                                   short* __restrict__ o) {
  __shared__ short Ks[64 * 64];
  __shared__ short Vt[64 * 64];
  __shared__ short Pt[4 * 16 * 64];
  int tid = threadIdx.x, lane = tid & 63, w = tid >> 6;
  int l16 = lane & 15, lhi = lane >> 4;
  int qb = blockIdx.x * 64;
  int bh = blockIdx.y;
  int b = bh >> 4, h = bh & 15;
  const size_t rbase = (size_t)b * 2048 * QKV_LD + (size_t)h * 64;

  unsigned vbase = (unsigned)(uintptr_t)&Vt[0];
  unsigned pbase = (unsigned)(uintptr_t)&Pt[0] + (unsigned)w * 2048;  // bytes

  // Q fragments in registers (A operand: row = lane&15, k-contig)
  s8v qf[2];
  int qrow = qb + w * 16 + l16;
#pragma unroll
  for (int kk = 0; kk < 2; ++kk)
    qf[kk] = *(const s8v*)&q[rbase + (size_t)qrow * QKV_LD + kk * 32 + lhi * 8];

  const f4v fzero = {0.f, 0.f, 0.f, 0.f};
  f4v oacc[4];
  float mreg[4], lsum[4];
#pragma unroll
  for (int r = 0; r < 4; ++r) { oacc[r] = fzero; mreg[r] = -1e30f; lsum[r] = 0.f; }

  for (int kt = 0; kt < 2048; kt += 64) {
    __syncthreads();
    // ---- stage K and V via global_load_lds (2 chunks of 1024B each per wave)
#pragma unroll
    for (int i = 0; i < 2; ++i) {
      int ch = w * 2 + i;
      {  // K: lds slot (row, cs) holds K[kt+row][(cs^(row&7))*8 ..+7]
        int row = ch * 8 + (lane >> 3);
        int cs = lane & 7;
        int col = ((cs ^ (row & 7)) * 8);
        gload_lds16(&k[rbase + (size_t)(kt + row) * QKV_LD + col], &Ks[ch * 512]);
      }
      {  // V: tr-subtile layout, region nb = ch>>1
        int nb = ch >> 1, rem = (ch & 1) * 64 + lane;
        int g2 = rem >> 4, half = (rem >> 3) & 1, jj = (rem >> 1) & 3, c8 = rem & 1;
        int key = g2 * 8 + half * 4 + jj;
        gload_lds16(&v[rbase + (size_t)(kt + key) * QKV_LD + nb * 16 + c8 * 8],
                    &Vt[ch * 512]);
      }
    }
    __syncthreads();

    // ---- S = (Q @ K^T) for 16 q-rows x 64 keys per wave
    f4v s_[4];
#pragma unroll
    for (int nb = 0; nb < 4; ++nb) s_[nb] = fzero;
#pragma unroll
    for (int kk = 0; kk < 2; ++kk) {
#pragma unroll
      for (int nb = 0; nb < 4; ++nb) {
        int key = nb * 16 + l16;
        int col = kk * 32 + lhi * 8;
        s8v kf = *(const s8v*)&Ks[key * 64 + (col ^ ((key & 7) << 3))];
        s_[nb] = __builtin_amdgcn_mfma_f32_16x16x32_bf16(qf[kk], kf, s_[nb], 0, 0, 0);
      }
    }

    // ---- online softmax (row = lhi*4 + r; 16-lane groups share rows)
    float pp[4][4], sc_[4];
#pragma unroll
    for (int r = 0; r < 4; ++r) {
      float mt = fmaxf(fmaxf(s_[0][r], s_[1][r]), fmaxf(s_[2][r], s_[3][r])) * 0.125f;
#pragma unroll
      for (int off = 1; off < 16; off <<= 1) mt = fmaxf(mt, __shfl_xor(mt, off));
      float newm = fmaxf(mreg[r], mt);
      float sc = __expf(mreg[r] - newm);
      mreg[r] = newm;
      float rowsum = 0.f;
#pragma unroll
      for (int nb = 0; nb < 4; ++nb) {
        float pvv = __expf(s_[nb][r] * 0.125f - newm);
        pp[nb][r] = pvv;
        rowsum += pvv;
      }
#pragma unroll
      for (int off = 1; off < 16; off <<= 1) rowsum += __shfl_xor(rowsum, off);
      lsum[r] = lsum[r] * sc + rowsum;
      sc_[r] = sc;
    }
#pragma unroll
    for (int nb = 0; nb < 4; ++nb)
#pragma unroll
      for (int r = 0; r < 4; ++r) oacc[nb][r] *= sc_[r];

    // ---- write P in tr-subtile layout: 4 x 8B vector writes
#pragma unroll
    for (int nb = 0; nb < 4; ++nb) {
      s4v pv;
#pragma unroll
      for (int r = 0; r < 4; ++r) pv[r] = f2bf(pp[nb][r]);
      int key = nb * 16 + l16;
      int ae = (key >> 3) * 128 + ((key >> 2) & 1) * 64 + (key & 3) * 16 + lhi * 4;
      *(s4v*)&Pt[w * 1024 + ae] = pv;
    }
    asm volatile("" ::: "memory");   // pin P stores before tr reads

    // ---- O += P @ V  (tr reads; manual waitcnt per rule 18)
#pragma unroll
    for (int kk2 = 0; kk2 < 2; ++kk2) {
      unsigned pb = pbase + 2u * ((kk2 * 4 + lhi) * 128 + l16);
      s4v p1 = ds_tr16(pb);
      s4v p2 = ds_tr16(pb + 128);
      s4v vr[4][2];
#pragma unroll
      for (int nb = 0; nb < 4; ++nb) {
        unsigned vb_ = vbase + 2u * (nb * 1024 + (kk2 * 4 + lhi) * 128 + l16);
        vr[nb][0] = ds_tr16(vb_);
        vr[nb][1] = ds_tr16(vb_ + 128);
      }
      asm volatile("s_waitcnt lgkmcnt(0)");
      __builtin_amdgcn_sched_barrier(0);
      s8v pf = cat8(p1, p2);
#pragma unroll
      for (int nb = 0; nb < 4; ++nb)
        oacc[nb] = __builtin_amdgcn_mfma_f32_16x16x32_bf16(
            pf, cat8(vr[nb][0], vr[nb][1]), oacc[nb], 0, 0, 0);
    }
  }

  // ---- normalize + store (o is [4096][1024] bf16)
#pragma unroll
  for (int nb = 0; nb < 4; ++nb)
#pragma unroll
    for (int r = 0; r < 4; ++r) {
      float ov = oacc[nb][r] / lsum[r];
      int qr2 = qb + w * 16 + lhi * 4 + r;
      o[((size_t)b * 2048 + qr2) * 1024 + h * 64 + nb * 16 + l16] = f2bf(ov);
    }
}

// ---------------------------------------------------------------------------
extern "C" void kernel_launch(void* const* d_in, const int* in_sizes, int n_in,
                              void* d_out, int out_size, void* d_ws, size_t ws_size,
                              hipStream_t stream) {
  (void)in_sizes; (void)n_in; (void)out_size; (void)ws_size;
  const float* x    = (const float*)d_in[0];
  const float* ln1g = (const float*)d_in[1];
  const float* ln1b = (const float*)d_in[2];
  const float* wq   = (const float*)d_in[3];
  const float* wk   = (const float*)d_in[4];
  const float* wv   = (const float*)d_in[5];
  const float* wo   = (const float*)d_in[6];
  const float* bo   = (const float*)d_in[7];
  const float* ln2g = (const float*)d_in[8];
  const float* ln2b = (const float*)d_in[9];
  const float* w1   = (const float*)d_in[10];
  const float* b1   = (const float*)d_in[11];
  const float* w2   = (const float*)d_in[12];
  const float* b2   = (const float*)d_in[13];
  float* out = (float*)d_out;

  char* ws = (char*)d_ws;
  const size_t MB = 1024 * 1024;
  short* h1   = (short*)(ws);                 // 8MB  [4096][1024]
  short* qkv  = (short*)(ws + 8 * MB);        // 24MB [4096][3072]
  short* mid  = (short*)(ws);                 // 32MB [4096][4096] (after attn)
  short* at   = (short*)(ws + 32 * MB);       // 8MB  [4096][1024]
  short* h2   = (short*)(ws + 32 * MB);       // reuses at after proj
  float* x2   = (float*)(ws + 40 * MB);       // 16MB f32 residual
  short* wqkvT = (short*)(ws + 56 * MB);      // 6MB  [3072][1024]
  short* wqT  = wqkvT;
  short* wkT  = wqkvT + 1024 * 1024;
  short* wvT  = wqkvT + 2 * 1024 * 1024;
  short* woT  = (short*)(ws + 62 * MB);       // 2MB
  short* w1T  = (short*)(ws + 64 * MB);       // 8MB  [4096][1024]
  short* w2T  = (short*)(ws + 72 * MB);       // 8MB  [1024][4096]

  dim3 tb(32, 8);
  wt_kernel<<<dim3(32, 32), tb, 0, stream>>>(wq, wqT, 1024, 1024);
  wt_kernel<<<dim3(32, 32), tb, 0, stream>>>(wk, wkT, 1024, 1024);
  wt_kernel<<<dim3(32, 32), tb, 0, stream>>>(wv, wvT, 1024, 1024);
  wt_kernel<<<dim3(32, 32), tb, 0, stream>>>(wo, woT, 1024, 1024);
  wt_kernel<<<dim3(128, 32), tb, 0, stream>>>(w1, w1T, 1024, 4096);
  wt_kernel<<<dim3(32, 128), tb, 0, stream>>>(w2, w2T, 4096, 1024);

  ln_kernel<<<M_ROWS, 256, 0, stream>>>(x, ln1g, ln1b, h1);

  // fused QKV: [4096][3072]
  gemm_kernel<0><<<dim3(24, 32), 256, 0, stream>>>(h1, wqkvT, nullptr, nullptr,
                                                   qkv, M_ROWS, QKV_LD, DM);

  attn_kernel<<<dim3(32, 32), 256, 0, stream>>>(qkv, qkv + 1024, qkv + 2048, at);

  gemm_kernel<1><<<dim3(8, 32), 256, 0, stream>>>(at, woT, bo, x, x2, M_ROWS, DM, DM);

  ln_kernel<<<M_ROWS, 256, 0, stream>>>(x2, ln2g, ln2b, h2);

  gemm_kernel<2><<<dim3(32, 32), 256, 0, stream>>>(h2, w1T, b1, nullptr, mid,
                                                   M_ROWS, FF, DM);

  gemm_kernel<1><<<dim3(8, 32), 256, 0, stream>>>(mid, w2T, b2, x2, out,
                                                  M_ROWS, DM, FF);
}

// Round 4
// 334.542 us; speedup vs baseline: 1.2825x; 1.1237x over previous
//
#include <hip/hip_runtime.h>
#include <math.h>

// Transformer block: pre-LN attn + residual, pre-LN MLP(GELU) + residual.
// B=2,S=2048,D=1024,H=16,hd=64,F=4096. fp32 in/out, bf16 MFMA compute.

typedef __attribute__((ext_vector_type(8))) short s8v;    // 8 x bf16 (16B)
typedef __attribute__((ext_vector_type(4))) short s4v;    // 4 x bf16 (8B)
typedef __attribute__((ext_vector_type(4))) float f4v;    // 16x16 MFMA acc
typedef __attribute__((ext_vector_type(16))) float f16v;  // 32x32 MFMA acc

#define M_ROWS 4096
#define DM 1024
#define FF 4096
#define QKV_LD 3072   // fused qkv row stride

__device__ inline short f2bf(float f) {
  unsigned u = __builtin_bit_cast(unsigned, f);
  u += 0x7fff + ((u >> 16) & 1);          // round-to-nearest-even
  return (short)(u >> 16);
}

// async global->LDS, 16B per lane. dst wave-uniform base; HW writes
// base + lane*16. src is per-lane.
__device__ inline void gload_lds16(const void* g, void* lds) {
  __builtin_amdgcn_global_load_lds(
      (const __attribute__((address_space(1))) unsigned*)(uintptr_t)g,
      (__attribute__((address_space(3))) unsigned*)(unsigned)(uintptr_t)lds,
      16, 0, 0);
}

// hardware transpose read: lane gathers 4 bf16 at elems addr/2 + {0,16,32,48}
// (verified per-lane-gather semantics — round-3 kernel passed with this).
__device__ inline s4v ds_tr16(unsigned off) {
  s4v r;
  asm volatile("ds_read_b64_tr_b16 %0, %1" : "=v"(r) : "v"(off));
  return r;
}

__device__ inline s8v cat8(s4v a, s4v b) {
  return __builtin_shufflevector(a, b, 0, 1, 2, 3, 4, 5, 6, 7);
}

// v_cvt_pk_bf16_f32: lo16 = bf16(a), hi16 = bf16(b)  (T12 recipe)
__device__ inline unsigned pkbf(float a, float b) {
  unsigned r;
  asm("v_cvt_pk_bf16_f32 %0, %1, %2" : "=v"(r) : "v"(a), "v"(b));
  return r;
}

// ---------------- weight transpose+convert: W[K][N] f32 -> Wt[N][K] bf16 ----
__global__ void wt_kernel(const float* __restrict__ W, short* __restrict__ Wt,
                          int K, int N) {
  __shared__ float tile[32][33];
  int tx = threadIdx.x, ty = threadIdx.y;            // (32,8)
  int n0 = blockIdx.x * 32, k0 = blockIdx.y * 32;
#pragma unroll
  for (int i = 0; i < 4; ++i)
    tile[ty + 8 * i][tx] = W[(size_t)(k0 + ty + 8 * i) * N + n0 + tx];
  __syncthreads();
#pragma unroll
  for (int i = 0; i < 4; ++i)
    Wt[(size_t)(n0 + ty + 8 * i) * K + k0 + tx] = f2bf(tile[tx][ty + 8 * i]);
}

// ---------------- LayerNorm: f32 [rows][1024] -> bf16 ----------------------
__global__ __launch_bounds__(256) void ln_kernel(const float* __restrict__ x,
                                                 const float* __restrict__ g,
                                                 const float* __restrict__ b,
                                                 short* __restrict__ out) {
  int row = blockIdx.x, tid = threadIdx.x;
  const float4* xr = (const float4*)(x + (size_t)row * DM);
  float4 v = xr[tid];                                 // 256 threads * 4 = 1024
  float s = v.x + v.y + v.z + v.w;
  float q = v.x * v.x + v.y * v.y + v.z * v.z + v.w * v.w;
#pragma unroll
  for (int off = 32; off; off >>= 1) {
    s += __shfl_down(s, off);
    q += __shfl_down(q, off);
  }
  __shared__ float red[8];
  if ((tid & 63) == 0) { red[tid >> 6] = s; red[4 + (tid >> 6)] = q; }
  __syncthreads();
  if (tid == 0) {
    float S = red[0] + red[1] + red[2] + red[3];
    float Q = red[4] + red[5] + red[6] + red[7];
    float mean = S * (1.0f / DM);
    float var = Q * (1.0f / DM) - mean * mean;
    red[0] = mean;
    red[1] = rsqrtf(var + 1e-5f);
  }
  __syncthreads();
  float mean = red[0], rstd = red[1];
  float4 gv = ((const float4*)g)[tid], bv = ((const float4*)b)[tid];
  s4v o;
  o[0] = f2bf((v.x - mean) * rstd * gv.x + bv.x);
  o[1] = f2bf((v.y - mean) * rstd * gv.y + bv.y);
  o[2] = f2bf((v.z - mean) * rstd * gv.z + bv.z);
  o[3] = f2bf((v.w - mean) * rstd * gv.w + bv.w);
  *(s4v*)&out[(size_t)row * DM + tid * 4] = o;
}

// ---------------- GEMM (m97 structure): C = A[M,K] @ Bt[N,K]^T -------------
template <int EPI>
__global__ __launch_bounds__(256) void gemm_kernel(
    const short* __restrict__ A, const short* __restrict__ Bt,
    const float* __restrict__ bias, const float* __restrict__ res,
    void* __restrict__ Cout, int M, int N, int K) {
  __shared__ short As[128 * 64];
  __shared__ short Bs[128 * 64];
  int tid = threadIdx.x, lane = tid & 63, wave = tid >> 6;
  int wr = wave >> 1, wc = wave & 1;
  int l16 = lane & 15, lhi = lane >> 4;
  int row0 = blockIdx.y * 128, col0 = blockIdx.x * 128;
  int lrow = lane >> 3, lcol8 = (lane & 7) * 8;     // staging lane coords

  const f4v fzero = {0.f, 0.f, 0.f, 0.f};
  f4v acc[4][4];
#pragma unroll
  for (int m = 0; m < 4; ++m)
#pragma unroll
    for (int n = 0; n < 4; ++n) acc[m][n] = fzero;

  for (int k0 = 0; k0 < K; k0 += 64) {
    __syncthreads();
#pragma unroll
    for (int i = 0; i < 4; ++i) {       // 16 chunks of 1024B per matrix
      int ch = wave * 4 + i;
      int row = ch * 8 + lrow;
      gload_lds16(&A[(size_t)(row0 + row) * K + k0 + lcol8], &As[ch * 512]);
      gload_lds16(&Bt[(size_t)(col0 + row) * K + k0 + lcol8], &Bs[ch * 512]);
    }
    __syncthreads();
#pragma unroll
    for (int kk = 0; kk < 2; ++kk) {
      s8v af[4], bfr[4];
#pragma unroll
      for (int m = 0; m < 4; ++m)
        af[m] = *(const s8v*)&As[(wr * 64 + m * 16 + l16) * 64 + kk * 32 + lhi * 8];
#pragma unroll
      for (int n = 0; n < 4; ++n)
        bfr[n] = *(const s8v*)&Bs[(wc * 64 + n * 16 + l16) * 64 + kk * 32 + lhi * 8];
#pragma unroll
      for (int m = 0; m < 4; ++m)
#pragma unroll
        for (int n = 0; n < 4; ++n)
          acc[m][n] = __builtin_amdgcn_mfma_f32_16x16x32_bf16(af[m], bfr[n],
                                                              acc[m][n], 0, 0, 0);
    }
  }
  // epilogue: D layout col=lane&15, row=(lane>>4)*4+reg
#pragma unroll
  for (int m = 0; m < 4; ++m)
#pragma unroll
    for (int n = 0; n < 4; ++n)
#pragma unroll
      for (int r = 0; r < 4; ++r) {
        int row = row0 + wr * 64 + m * 16 + lhi * 4 + r;
        int col = col0 + wc * 64 + n * 16 + l16;
        size_t idx = (size_t)row * N + col;
        float v = acc[m][n][r];
        if (EPI == 0) {
          ((short*)Cout)[idx] = f2bf(v);
        } else if (EPI == 1) {
          ((float*)Cout)[idx] = v + bias[col] + res[idx];
        } else {
          float t = v + bias[col];
          t = 0.5f * t * (1.0f + erff(t * 0.70710678118f));
          ((short*)Cout)[idx] = f2bf(t);
        }
      }
}

// ---------------- Flash attention (swapped QK^T, in-register softmax) -------
// q,k,v point into fused qkv [4096][3072]. grid (S/128, B*H), 4 waves x 32 q.
// 32x32x16 MFMA. T = mfma(K,Q) -> T[key][qrow]: lane owns qrow = lane&31,
// keys {(r&3)+8*(r>>2)+4*(lane>>5)} (+32 for t1); partner lane^32 owns rest.
// Softmax fully in-register; P -> PV B-frag via cvt_pk + shfl_xor(32).
// O^T = mfma(V^T, P^T); V^T via tr-subtile LDS layout + ds_read_b64_tr_b16.
__global__ __launch_bounds__(256) void attn_kernel(const short* __restrict__ q,
                                                   const short* __restrict__ k,
                                                   const short* __restrict__ v,
                                                   short* __restrict__ o) {
  __shared__ short Ks[64 * 64];     // [key][d] XOR-swizzled (16B granules)
  __shared__ short Vt[64 * 64];     // 4 regions [64 key][16 d] stride-16
  int tid = threadIdx.x, lane = tid & 63, w = tid >> 6;
  int l31 = lane & 31, l15 = lane & 15, h = lane >> 5;
  int qb = blockIdx.x * 128;
  int bh = blockIdx.y;
  int b = bh >> 4, hh = bh & 15;
  const size_t rbase = (size_t)b * 2048 * QKV_LD + (size_t)hh * 64;
  unsigned vtb = (unsigned)(uintptr_t)&Vt[0];

  // Q B-fragments: lane holds Q[qrow][16c + 8h .. +8]
  int qrow = qb + w * 32 + l31;
  s8v qf[4];
#pragma unroll
  for (int c = 0; c < 4; ++c)
    qf[c] = *(const s8v*)&q[rbase + (size_t)qrow * QKV_LD + c * 16 + h * 8];

  f16v o0, o1;
#pragma unroll
  for (int i = 0; i < 16; ++i) { o0[i] = 0.f; o1[i] = 0.f; }
  float mreg = -3.0e38f, lsum = 0.f;

  for (int kt = 0; kt < 2048; kt += 64) {
    __syncthreads();
    // ---- stage K and V via global_load_lds (2+2 chunks of 1024B per wave)
#pragma unroll
    for (int i = 0; i < 2; ++i) {
      int ch = w * 2 + i;
      {  // K: granule (row, s) holds source granule s^(row&7)
        int row = ch * 8 + (lane >> 3);
        int cs = lane & 7;
        int col = ((cs ^ (row & 7)) * 8);
        gload_lds16(&k[rbase + (size_t)(kt + row) * QKV_LD + col], &Ks[ch * 512]);
      }
      {  // V: region nb = ch>>1 holds [key][16 d] stride-16
        int nb = ch >> 1, rem = (ch & 1) * 64 + lane;
        int key = rem >> 1, c8 = rem & 1;
        gload_lds16(&v[rbase + (size_t)(kt + key) * QKV_LD + nb * 16 + c8 * 8],
                    &Vt[ch * 512]);
      }
    }
    __syncthreads();

    // ---- T = K @ Q^T (swapped): t0 keys 0..31, t1 keys 32..63
    f16v t0, t1;
#pragma unroll
    for (int i = 0; i < 16; ++i) { t0[i] = 0.f; t1[i] = 0.f; }
    __builtin_amdgcn_s_setprio(1);
#pragma unroll
    for (int c = 0; c < 4; ++c) {
      int slot = ((2 * c + h) ^ (l31 & 7)) * 8;
      s8v k0f = *(const s8v*)&Ks[l31 * 64 + slot];
      s8v k1f = *(const s8v*)&Ks[(32 + l31) * 64 + slot];
      t0 = __builtin_amdgcn_mfma_f32_32x32x16_bf16(k0f, qf[c], t0, 0, 0, 0);
      t1 = __builtin_amdgcn_mfma_f32_32x32x16_bf16(k1f, qf[c], t1, 0, 0, 0);
    }
    __builtin_amdgcn_s_setprio(0);

    // ---- in-register online softmax for qrow = l31 (raw scores, scale .125)
    float mx[8];
#pragma unroll
    for (int i = 0; i < 8; ++i)
      mx[i] = fmaxf(fmaxf(t0[i], t0[i + 8]), fmaxf(t1[i], t1[i + 8]));
    float rm = fmaxf(fmaxf(fmaxf(mx[0], mx[1]), fmaxf(mx[2], mx[3])),
                     fmaxf(fmaxf(mx[4], mx[5]), fmaxf(mx[6], mx[7])));
    rm = fmaxf(rm, __shfl_xor(rm, 32));
    float newm = fmaxf(mreg, rm);
    float sc = __expf((mreg - newm) * 0.125f);
    float ms = newm * 0.125f;
    mreg = newm;
#pragma unroll
    for (int i = 0; i < 16; ++i) {
      t0[i] = __expf(fmaf(t0[i], 0.125f, -ms));
      t1[i] = __expf(fmaf(t1[i], 0.125f, -ms));
    }
    float sm[8];
#pragma unroll
    for (int i = 0; i < 8; ++i)
      sm[i] = (t0[i] + t0[i + 8]) + (t1[i] + t1[i + 8]);
    float rs = ((sm[0] + sm[1]) + (sm[2] + sm[3])) +
               ((sm[4] + sm[5]) + (sm[6] + sm[7]));
    rs += __shfl_xor(rs, 32);
    lsum = lsum * sc + rs;

    // ---- build PV B-fragments: keys 16c + 8h' + 0..7 per chunk c
    s8v pB[4];
#pragma unroll
    for (int c = 0; c < 4; ++c) {
      int rb = (c & 1) * 8;
      float e0, e1, e2, e3, e4, e5, e6, e7;
      if (c < 2) {
        e0 = t0[rb]; e1 = t0[rb + 1]; e2 = t0[rb + 2]; e3 = t0[rb + 3];
        e4 = t0[rb + 4]; e5 = t0[rb + 5]; e6 = t0[rb + 6]; e7 = t0[rb + 7];
      } else {
        e0 = t1[rb]; e1 = t1[rb + 1]; e2 = t1[rb + 2]; e3 = t1[rb + 3];
        e4 = t1[rb + 4]; e5 = t1[rb + 5]; e6 = t1[rb + 6]; e7 = t1[rb + 7];
      }
      unsigned wA0 = pkbf(e0, e1), wA1 = pkbf(e2, e3);
      unsigned wB0 = pkbf(e4, e5), wB1 = pkbf(e6, e7);
      unsigned s0 = h ? wA0 : wB0, s1 = h ? wA1 : wB1;
      unsigned r0 = __shfl_xor(s0, 32), r1 = __shfl_xor(s1, 32);
      uint4 ww;
      ww.x = h ? r0 : wA0;
      ww.y = h ? r1 : wA1;
      ww.z = h ? wB0 : r0;
      ww.w = h ? wB1 : r1;
      pB[c] = __builtin_bit_cast(s8v, ww);
    }

    // ---- V^T A-fragments via tr reads (issue all, rescale O in shadow)
    s4v va[2][4][2];
#pragma unroll
    for (int db = 0; db < 2; ++db) {
      unsigned base = vtb + (unsigned)(db * 2 + (l31 >> 4)) * 2048 + 2u * l15;
#pragma unroll
      for (int c = 0; c < 4; ++c) {
        unsigned a = base + (unsigned)(c * 512 + h * 256);  // k0*32 bytes
        va[db][c][0] = ds_tr16(a);
        va[db][c][1] = ds_tr16(a + 128);
      }
    }
#pragma unroll
    for (int i = 0; i < 16; ++i) { o0[i] *= sc; o1[i] *= sc; }
    asm volatile("s_waitcnt lgkmcnt(0)");
    __builtin_amdgcn_sched_barrier(0);
    __builtin_amdgcn_s_setprio(1);
#pragma unroll
    for (int c = 0; c < 4; ++c) {
      o0 = __builtin_amdgcn_mfma_f32_32x32x16_bf16(cat8(va[0][c][0], va[0][c][1]),
                                                   pB[c], o0, 0, 0, 0);
      o1 = __builtin_amdgcn_mfma_f32_32x32x16_bf16(cat8(va[1][c][0], va[1][c][1]),
                                                   pB[c], o1, 0, 0, 0);
    }
    __builtin_amdgcn_s_setprio(0);
  }

  // ---- normalize + store: lane owns qrow=l31; d = db*32 + 8q + 4h + 0..3
  float inv = 1.0f / lsum;
  size_t obase = ((size_t)b * 2048 + qrow) * 1024 + hh * 64;
#pragma unroll
  for (int db = 0; db < 2; ++db)
#pragma unroll
    for (int qq = 0; qq < 4; ++qq) {
      s4v pv;
#pragma unroll
      for (int i = 0; i < 4; ++i) {
        float val = (db == 0 ? o0[qq * 4 + i] : o1[qq * 4 + i]) * inv;
        pv[i] = f2bf(val);
      }
      *(s4v*)&o[obase + db * 32 + qq * 8 + h * 4] = pv;
    }
}

// ---------------------------------------------------------------------------
extern "C" void kernel_launch(void* const* d_in, const int* in_sizes, int n_in,
                              void* d_out, int out_size, void* d_ws, size_t ws_size,
                              hipStream_t stream) {
  (void)in_sizes; (void)n_in; (void)out_size; (void)ws_size;
  const float* x    = (const float*)d_in[0];
  const float* ln1g = (const float*)d_in[1];
  const float* ln1b = (const float*)d_in[2];
  const float* wq   = (const float*)d_in[3];
  const float* wk   = (const float*)d_in[4];
  const float* wv   = (const float*)d_in[5];
  const float* wo   = (const float*)d_in[6];
  const float* bo   = (const float*)d_in[7];
  const float* ln2g = (const float*)d_in[8];
  const float* ln2b = (const float*)d_in[9];
  const float* w1   = (const float*)d_in[10];
  const float* b1   = (const float*)d_in[11];
  const float* w2   = (const float*)d_in[12];
  const float* b2   = (const float*)d_in[13];
  float* out = (float*)d_out;

  char* ws = (char*)d_ws;
  const size_t MB = 1024 * 1024;
  short* h1   = (short*)(ws);                 // 8MB  [4096][1024]
  short* qkv  = (short*)(ws + 8 * MB);        // 24MB [4096][3072]
  short* mid  = (short*)(ws);                 // 32MB [4096][4096] (after attn)
  short* at   = (short*)(ws + 32 * MB);       // 8MB  [4096][1024]
  short* h2   = (short*)(ws + 32 * MB);       // reuses at after proj
  float* x2   = (float*)(ws + 40 * MB);       // 16MB f32 residual
  short* wqkvT = (short*)(ws + 56 * MB);      // 6MB  [3072][1024]
  short* wqT  = wqkvT;
  short* wkT  = wqkvT + 1024 * 1024;
  short* wvT  = wqkvT + 2 * 1024 * 1024;
  short* woT  = (short*)(ws + 62 * MB);       // 2MB
  short* w1T  = (short*)(ws + 64 * MB);       // 8MB  [4096][1024]
  short* w2T  = (short*)(ws + 72 * MB);       // 8MB  [1024][4096]

  dim3 tb(32, 8);
  wt_kernel<<<dim3(32, 32), tb, 0, stream>>>(wq, wqT, 1024, 1024);
  wt_kernel<<<dim3(32, 32), tb, 0, stream>>>(wk, wkT, 1024, 1024);
  wt_kernel<<<dim3(32, 32), tb, 0, stream>>>(wv, wvT, 1024, 1024);
  wt_kernel<<<dim3(32, 32), tb, 0, stream>>>(wo, woT, 1024, 1024);
  wt_kernel<<<dim3(128, 32), tb, 0, stream>>>(w1, w1T, 1024, 4096);
  wt_kernel<<<dim3(32, 128), tb, 0, stream>>>(w2, w2T, 4096, 1024);

  ln_kernel<<<M_ROWS, 256, 0, stream>>>(x, ln1g, ln1b, h1);

  // fused QKV: [4096][3072]
  gemm_kernel<0><<<dim3(24, 32), 256, 0, stream>>>(h1, wqkvT, nullptr, nullptr,
                                                   qkv, M_ROWS, QKV_LD, DM);

  attn_kernel<<<dim3(16, 32), 256, 0, stream>>>(qkv, qkv + 1024, qkv + 2048, at);

  gemm_kernel<1><<<dim3(8, 32), 256, 0, stream>>>(at, woT, bo, x, x2, M_ROWS, DM, DM);

  ln_kernel<<<M_ROWS, 256, 0, stream>>>(x2, ln2g, ln2b, h2);

  gemm_kernel<2><<<dim3(32, 32), 256, 0, stream>>>(h2, w1T, b1, nullptr, mid,
                                                   M_ROWS, FF, DM);

  gemm_kernel<1><<<dim3(8, 32), 256, 0, stream>>>(mid, w2T, b2, x2, out,
                                                  M_ROWS, DM, FF);
}

// Round 5
// 277.406 us; speedup vs baseline: 1.5466x; 1.2060x over previous
//
#include <hip/hip_runtime.h>
#include <math.h>

// Transformer block: pre-LN attn + residual, pre-LN MLP(GELU) + residual.
// B=2,S=2048,D=1024,H=16,hd=64,F=4096. fp32 in/out, bf16 MFMA compute.

typedef __attribute__((ext_vector_type(8))) short s8v;    // 8 x bf16 (16B)
typedef __attribute__((ext_vector_type(4))) short s4v;    // 4 x bf16 (8B)
typedef __attribute__((ext_vector_type(4))) float f4v;    // 16x16 MFMA acc
typedef __attribute__((ext_vector_type(16))) float f16v;  // 32x32 MFMA acc

#define M_ROWS 4096
#define DM 1024
#define FF 4096
#define QKV_LD 3072   // fused qkv row stride

__device__ inline short f2bf(float f) {
  unsigned u = __builtin_bit_cast(unsigned, f);
  u += 0x7fff + ((u >> 16) & 1);          // round-to-nearest-even
  return (short)(u >> 16);
}

// async global->LDS, 16B per lane. dst wave-uniform base; HW writes
// base + lane*16. src is per-lane.
__device__ inline void gload_lds16(const void* g, void* lds) {
  __builtin_amdgcn_global_load_lds(
      (const __attribute__((address_space(1))) unsigned*)(uintptr_t)g,
      (__attribute__((address_space(3))) unsigned*)(unsigned)(uintptr_t)lds,
      16, 0, 0);
}

// hardware transpose read: lane gathers 4 bf16 (verified round-3/4 passing).
__device__ inline s4v ds_tr16(unsigned off) {
  s4v r;
  asm volatile("ds_read_b64_tr_b16 %0, %1" : "=v"(r) : "v"(off));
  return r;
}

__device__ inline s8v cat8(s4v a, s4v b) {
  return __builtin_shufflevector(a, b, 0, 1, 2, 3, 4, 5, 6, 7);
}

// v_cvt_pk_bf16_f32: lo16 = bf16(a), hi16 = bf16(b)  (T12 recipe)
__device__ inline unsigned pkbf(float a, float b) {
  unsigned r;
  asm("v_cvt_pk_bf16_f32 %0, %1, %2" : "=v"(r) : "v"(a), "v"(b));
  return r;
}

// tanh-approx GELU (max err ~3e-3 vs erf-GELU; cheap on VALU)
__device__ inline float gelu_t(float x) {
  float x3 = x * x * x;
  float z = fmaf(x3, 0.044715f, x) * 1.5957691216f;  // 2*0.7978845608
  float e = __expf(z);                               // tanh via sigmoid form
  float th = fmaf(-2.0f, __frcp_rn(e + 1.0f), 1.0f); // 1 - 2/(e^2z+1)
  return 0.5f * x * (1.0f + th);
}

// ---------------- weight transpose+convert: W[K][N] f32 -> Wt[N][K] bf16 ----
__global__ void wt_kernel(const float* __restrict__ W, short* __restrict__ Wt,
                          int K, int N) {
  __shared__ float tile[32][33];
  int tx = threadIdx.x, ty = threadIdx.y;            // (32,8)
  int n0 = blockIdx.x * 32, k0 = blockIdx.y * 32;
#pragma unroll
  for (int i = 0; i < 4; ++i)
    tile[ty + 8 * i][tx] = W[(size_t)(k0 + ty + 8 * i) * N + n0 + tx];
  __syncthreads();
#pragma unroll
  for (int i = 0; i < 4; ++i)
    Wt[(size_t)(n0 + ty + 8 * i) * K + k0 + tx] = f2bf(tile[tx][ty + 8 * i]);
}

// ---------------- LayerNorm: f32 [rows][1024] -> bf16 ----------------------
__global__ __launch_bounds__(256) void ln_kernel(const float* __restrict__ x,
                                                 const float* __restrict__ g,
                                                 const float* __restrict__ b,
                                                 short* __restrict__ out) {
  int row = blockIdx.x, tid = threadIdx.x;
  const float4* xr = (const float4*)(x + (size_t)row * DM);
  float4 v = xr[tid];                                 // 256 threads * 4 = 1024
  float s = v.x + v.y + v.z + v.w;
  float q = v.x * v.x + v.y * v.y + v.z * v.z + v.w * v.w;
#pragma unroll
  for (int off = 32; off; off >>= 1) {
    s += __shfl_down(s, off);
    q += __shfl_down(q, off);
  }
  __shared__ float red[8];
  if ((tid & 63) == 0) { red[tid >> 6] = s; red[4 + (tid >> 6)] = q; }
  __syncthreads();
  if (tid == 0) {
    float S = red[0] + red[1] + red[2] + red[3];
    float Q = red[4] + red[5] + red[6] + red[7];
    float mean = S * (1.0f / DM);
    float var = Q * (1.0f / DM) - mean * mean;
    red[0] = mean;
    red[1] = rsqrtf(var + 1e-5f);
  }
  __syncthreads();
  float mean = red[0], rstd = red[1];
  float4 gv = ((const float4*)g)[tid], bv = ((const float4*)b)[tid];
  s4v o;
  o[0] = f2bf((v.x - mean) * rstd * gv.x + bv.x);
  o[1] = f2bf((v.y - mean) * rstd * gv.y + bv.y);
  o[2] = f2bf((v.z - mean) * rstd * gv.z + bv.z);
  o[3] = f2bf((v.w - mean) * rstd * gv.w + bv.w);
  *(s4v*)&out[(size_t)row * DM + tid * 4] = o;
}

// ---------------- GEMM, 2-phase double-buffered (T3-minimum recipe) --------
// C[M,N] = A[M,K](bf16) @ Bt[N,K]^T(bf16). 128x128 tile, BK=64, 4 waves.
// One barrier per K-step: STAGE(next buf) issued BEFORE ds_read+MFMA of
// current buf; __syncthreads() (vmcnt+lgkm drain) retires the prefetch.
// EPI 0: C bf16 = acc
// EPI 1: C f32  = acc + bias[n] + res[m,n]
// EPI 2: C bf16 = gelu(acc + bias[n])
template <int EPI>
__global__ __launch_bounds__(256) void gemm_kernel(
    const short* __restrict__ A, const short* __restrict__ Bt,
    const float* __restrict__ bias, const float* __restrict__ res,
    void* __restrict__ Cout, int M, int N, int K) {
  __shared__ short As[2][128 * 64];
  __shared__ short Bs[2][128 * 64];
  int tid = threadIdx.x, lane = tid & 63, wave = tid >> 6;
  int wr = wave >> 1, wc = wave & 1;
  int l16 = lane & 15, lhi = lane >> 4;
  int row0 = blockIdx.y * 128, col0 = blockIdx.x * 128;
  int lrow = lane >> 3, lcol8 = (lane & 7) * 8;     // staging lane coords

  const f4v fzero = {0.f, 0.f, 0.f, 0.f};
  f4v acc[4][4];
#pragma unroll
  for (int m = 0; m < 4; ++m)
#pragma unroll
    for (int n = 0; n < 4; ++n) acc[m][n] = fzero;

  const int nt = K >> 6;

  // prologue: stage tile 0 into buf 0
#pragma unroll
  for (int i = 0; i < 4; ++i) {
    int ch = wave * 4 + i;
    int row = ch * 8 + lrow;
    gload_lds16(&A[(size_t)(row0 + row) * K + lcol8], &As[0][ch * 512]);
    gload_lds16(&Bt[(size_t)(col0 + row) * K + lcol8], &Bs[0][ch * 512]);
  }
  __syncthreads();   // drains vmcnt(0): buf 0 ready

  for (int t = 0; t < nt; ++t) {
    int cur = t & 1, nxt = cur ^ 1;
    if (t + 1 < nt) {
      int k1 = (t + 1) << 6;
#pragma unroll
      for (int i = 0; i < 4; ++i) {
        int ch = wave * 4 + i;
        int row = ch * 8 + lrow;
        gload_lds16(&A[(size_t)(row0 + row) * K + k1 + lcol8], &As[nxt][ch * 512]);
        gload_lds16(&Bt[(size_t)(col0 + row) * K + k1 + lcol8], &Bs[nxt][ch * 512]);
      }
    }
#pragma unroll
    for (int kk = 0; kk < 2; ++kk) {
      s8v af[4], bfr[4];
#pragma unroll
      for (int m = 0; m < 4; ++m)
        af[m] = *(const s8v*)&As[cur][(wr * 64 + m * 16 + l16) * 64 + kk * 32 + lhi * 8];
#pragma unroll
      for (int n = 0; n < 4; ++n)
        bfr[n] = *(const s8v*)&Bs[cur][(wc * 64 + n * 16 + l16) * 64 + kk * 32 + lhi * 8];
#pragma unroll
      for (int m = 0; m < 4; ++m)
#pragma unroll
        for (int n = 0; n < 4; ++n)
          acc[m][n] = __builtin_amdgcn_mfma_f32_16x16x32_bf16(af[m], bfr[n],
                                                              acc[m][n], 0, 0, 0);
    }
    __syncthreads();   // retires prefetch into nxt; releases cur for re-stage
  }

  // epilogue: D layout col=lane&15, row=(lane>>4)*4+reg
#pragma unroll
  for (int m = 0; m < 4; ++m)
#pragma unroll
    for (int n = 0; n < 4; ++n)
#pragma unroll
      for (int r = 0; r < 4; ++r) {
        int row = row0 + wr * 64 + m * 16 + lhi * 4 + r;
        int col = col0 + wc * 64 + n * 16 + l16;
        size_t idx = (size_t)row * N + col;
        float v = acc[m][n][r];
        if (EPI == 0) {
          ((short*)Cout)[idx] = f2bf(v);
        } else if (EPI == 1) {
          ((float*)Cout)[idx] = v + bias[col] + res[idx];
        } else {
          ((short*)Cout)[idx] = f2bf(gelu_t(v + bias[col]));
        }
      }
}

// ---------------- Flash attention (swapped QK^T, in-register softmax) -------
// q,k,v point into fused qkv [4096][3072]. grid (S/128, B*H), 4 waves x 32 q.
__global__ __launch_bounds__(256) void attn_kernel(const short* __restrict__ q,
                                                   const short* __restrict__ k,
                                                   const short* __restrict__ v,
                                                   short* __restrict__ o) {
  __shared__ short Ks[64 * 64];     // [key][d] XOR-swizzled (16B granules)
  __shared__ short Vt[64 * 64];     // 4 regions [64 key][16 d] stride-16
  int tid = threadIdx.x, lane = tid & 63, w = tid >> 6;
  int l31 = lane & 31, l15 = lane & 15, h = lane >> 5;
  int qb = blockIdx.x * 128;
  int bh = blockIdx.y;
  int b = bh >> 4, hh = bh & 15;
  const size_t rbase = (size_t)b * 2048 * QKV_LD + (size_t)hh * 64;
  unsigned vtb = (unsigned)(uintptr_t)&Vt[0];

  // Q B-fragments: lane holds Q[qrow][16c + 8h .. +8]
  int qrow = qb + w * 32 + l31;
  s8v qf[4];
#pragma unroll
  for (int c = 0; c < 4; ++c)
    qf[c] = *(const s8v*)&q[rbase + (size_t)qrow * QKV_LD + c * 16 + h * 8];

  f16v o0, o1;
#pragma unroll
  for (int i = 0; i < 16; ++i) { o0[i] = 0.f; o1[i] = 0.f; }
  float mreg = -3.0e38f, lsum = 0.f;

  for (int kt = 0; kt < 2048; kt += 64) {
    __syncthreads();
    // ---- stage K and V via global_load_lds (2+2 chunks of 1024B per wave)
#pragma unroll
    for (int i = 0; i < 2; ++i) {
      int ch = w * 2 + i;
      {  // K: granule (row, s) holds source granule s^(row&7)
        int row = ch * 8 + (lane >> 3);
        int cs = lane & 7;
        int col = ((cs ^ (row & 7)) * 8);
        gload_lds16(&k[rbase + (size_t)(kt + row) * QKV_LD + col], &Ks[ch * 512]);
      }
      {  // V: region nb = ch>>1 holds [key][16 d] stride-16
        int nb = ch >> 1, rem = (ch & 1) * 64 + lane;
        int key = rem >> 1, c8 = rem & 1;
        gload_lds16(&v[rbase + (size_t)(kt + key) * QKV_LD + nb * 16 + c8 * 8],
                    &Vt[ch * 512]);
      }
    }
    __syncthreads();

    // ---- T = K @ Q^T (swapped): t0 keys 0..31, t1 keys 32..63
    f16v t0, t1;
#pragma unroll
    for (int i = 0; i < 16; ++i) { t0[i] = 0.f; t1[i] = 0.f; }
    __builtin_amdgcn_s_setprio(1);
#pragma unroll
    for (int c = 0; c < 4; ++c) {
      int slot = ((2 * c + h) ^ (l31 & 7)) * 8;
      s8v k0f = *(const s8v*)&Ks[l31 * 64 + slot];
      s8v k1f = *(const s8v*)&Ks[(32 + l31) * 64 + slot];
      t0 = __builtin_amdgcn_mfma_f32_32x32x16_bf16(k0f, qf[c], t0, 0, 0, 0);
      t1 = __builtin_amdgcn_mfma_f32_32x32x16_bf16(k1f, qf[c], t1, 0, 0, 0);
    }
    __builtin_amdgcn_s_setprio(0);

    // ---- in-register online softmax for qrow = l31 (raw scores, scale .125)
    float mx[8];
#pragma unroll
    for (int i = 0; i < 8; ++i)
      mx[i] = fmaxf(fmaxf(t0[i], t0[i + 8]), fmaxf(t1[i], t1[i + 8]));
    float rm = fmaxf(fmaxf(fmaxf(mx[0], mx[1]), fmaxf(mx[2], mx[3])),
                     fmaxf(fmaxf(mx[4], mx[5]), fmaxf(mx[6], mx[7])));
    rm = fmaxf(rm, __shfl_xor(rm, 32));
    float newm = fmaxf(mreg, rm);
    float sc = __expf((mreg - newm) * 0.125f);
    float ms = newm * 0.125f;
    mreg = newm;
#pragma unroll
    for (int i = 0; i < 16; ++i) {
      t0[i] = __expf(fmaf(t0[i], 0.125f, -ms));
      t1[i] = __expf(fmaf(t1[i], 0.125f, -ms));
    }
    float sm[8];
#pragma unroll
    for (int i = 0; i < 8; ++i)
      sm[i] = (t0[i] + t0[i + 8]) + (t1[i] + t1[i + 8]);
    float rs = ((sm[0] + sm[1]) + (sm[2] + sm[3])) +
               ((sm[4] + sm[5]) + (sm[6] + sm[7]));
    rs += __shfl_xor(rs, 32);
    lsum = lsum * sc + rs;

    // ---- build PV B-fragments: keys 16c + 8h' + 0..7 per chunk c
    s8v pB[4];
#pragma unroll
    for (int c = 0; c < 4; ++c) {
      int rb = (c & 1) * 8;
      float e0, e1, e2, e3, e4, e5, e6, e7;
      if (c < 2) {
        e0 = t0[rb]; e1 = t0[rb + 1]; e2 = t0[rb + 2]; e3 = t0[rb + 3];
        e4 = t0[rb + 4]; e5 = t0[rb + 5]; e6 = t0[rb + 6]; e7 = t0[rb + 7];
      } else {
        e0 = t1[rb]; e1 = t1[rb + 1]; e2 = t1[rb + 2]; e3 = t1[rb + 3];
        e4 = t1[rb + 4]; e5 = t1[rb + 5]; e6 = t1[rb + 6]; e7 = t1[rb + 7];
      }
      unsigned wA0 = pkbf(e0, e1), wA1 = pkbf(e2, e3);
      unsigned wB0 = pkbf(e4, e5), wB1 = pkbf(e6, e7);
      unsigned s0 = h ? wA0 : wB0, s1 = h ? wA1 : wB1;
      unsigned r0 = __shfl_xor(s0, 32), r1 = __shfl_xor(s1, 32);
      uint4 ww;
      ww.x = h ? r0 : wA0;
      ww.y = h ? r1 : wA1;
      ww.z = h ? wB0 : r0;
      ww.w = h ? wB1 : r1;
      pB[c] = __builtin_bit_cast(s8v, ww);
    }

    // ---- V^T A-fragments via tr reads (issue all, rescale O in shadow)
    s4v va[2][4][2];
#pragma unroll
    for (int db = 0; db < 2; ++db) {
      unsigned base = vtb + (unsigned)(db * 2 + (l31 >> 4)) * 2048 + 2u * l15;
#pragma unroll
      for (int c = 0; c < 4; ++c) {
        unsigned a = base + (unsigned)(c * 512 + h * 256);  // k0*32 bytes
        va[db][c][0] = ds_tr16(a);
        va[db][c][1] = ds_tr16(a + 128);
      }
    }
#pragma unroll
    for (int i = 0; i < 16; ++i) { o0[i] *= sc; o1[i] *= sc; }
    asm volatile("s_waitcnt lgkmcnt(0)");
    __builtin_amdgcn_sched_barrier(0);
    __builtin_amdgcn_s_setprio(1);
#pragma unroll
    for (int c = 0; c < 4; ++c) {
      o0 = __builtin_amdgcn_mfma_f32_32x32x16_bf16(cat8(va[0][c][0], va[0][c][1]),
                                                   pB[c], o0, 0, 0, 0);
      o1 = __builtin_amdgcn_mfma_f32_32x32x16_bf16(cat8(va[1][c][0], va[1][c][1]),
                                                   pB[c], o1, 0, 0, 0);
    }
    __builtin_amdgcn_s_setprio(0);
  }

  // ---- normalize + store: lane owns qrow=l31; d = db*32 + 8q + 4h + 0..3
  float inv = 1.0f / lsum;
  size_t obase = ((size_t)b * 2048 + qrow) * 1024 + hh * 64;
#pragma unroll
  for (int db = 0; db < 2; ++db)
#pragma unroll
    for (int qq = 0; qq < 4; ++qq) {
      s4v pv;
#pragma unroll
      for (int i = 0; i < 4; ++i) {
        float val = (db == 0 ? o0[qq * 4 + i] : o1[qq * 4 + i]) * inv;
        pv[i] = f2bf(val);
      }
      *(s4v*)&o[obase + db * 32 + qq * 8 + h * 4] = pv;
    }
}

// ---------------------------------------------------------------------------
extern "C" void kernel_launch(void* const* d_in, const int* in_sizes, int n_in,
                              void* d_out, int out_size, void* d_ws, size_t ws_size,
                              hipStream_t stream) {
  (void)in_sizes; (void)n_in; (void)out_size; (void)ws_size;
  const float* x    = (const float*)d_in[0];
  const float* ln1g = (const float*)d_in[1];
  const float* ln1b = (const float*)d_in[2];
  const float* wq   = (const float*)d_in[3];
  const float* wk   = (const float*)d_in[4];
  const float* wv   = (const float*)d_in[5];
  const float* wo   = (const float*)d_in[6];
  const float* bo   = (const float*)d_in[7];
  const float* ln2g = (const float*)d_in[8];
  const float* ln2b = (const float*)d_in[9];
  const float* w1   = (const float*)d_in[10];
  const float* b1   = (const float*)d_in[11];
  const float* w2   = (const float*)d_in[12];
  const float* b2   = (const float*)d_in[13];
  float* out = (float*)d_out;

  char* ws = (char*)d_ws;
  const size_t MB = 1024 * 1024;
  short* h1   = (short*)(ws);                 // 8MB  [4096][1024]
  short* qkv  = (short*)(ws + 8 * MB);        // 24MB [4096][3072]
  short* mid  = (short*)(ws);                 // 32MB [4096][4096] (after attn)
  short* at   = (short*)(ws + 32 * MB);       // 8MB  [4096][1024]
  short* h2   = (short*)(ws + 32 * MB);       // reuses at after proj
  float* x2   = (float*)(ws + 40 * MB);       // 16MB f32 residual
  short* wqkvT = (short*)(ws + 56 * MB);      // 6MB  [3072][1024]
  short* wqT  = wqkvT;
  short* wkT  = wqkvT + 1024 * 1024;
  short* wvT  = wqkvT + 2 * 1024 * 1024;
  short* woT  = (short*)(ws + 62 * MB);       // 2MB
  short* w1T  = (short*)(ws + 64 * MB);       // 8MB  [4096][1024]
  short* w2T  = (short*)(ws + 72 * MB);       // 8MB  [1024][4096]

  dim3 tb(32, 8);
  wt_kernel<<<dim3(32, 32), tb, 0, stream>>>(wq, wqT, 1024, 1024);
  wt_kernel<<<dim3(32, 32), tb, 0, stream>>>(wk, wkT, 1024, 1024);
  wt_kernel<<<dim3(32, 32), tb, 0, stream>>>(wv, wvT, 1024, 1024);
  wt_kernel<<<dim3(32, 32), tb, 0, stream>>>(wo, woT, 1024, 1024);
  wt_kernel<<<dim3(128, 32), tb, 0, stream>>>(w1, w1T, 1024, 4096);
  wt_kernel<<<dim3(32, 128), tb, 0, stream>>>(w2, w2T, 4096, 1024);

  ln_kernel<<<M_ROWS, 256, 0, stream>>>(x, ln1g, ln1b, h1);

  // fused QKV: [4096][3072]
  gemm_kernel<0><<<dim3(24, 32), 256, 0, stream>>>(h1, wqkvT, nullptr, nullptr,
                                                   qkv, M_ROWS, QKV_LD, DM);

  attn_kernel<<<dim3(16, 32), 256, 0, stream>>>(qkv, qkv + 1024, qkv + 2048, at);

  gemm_kernel<1><<<dim3(8, 32), 256, 0, stream>>>(at, woT, bo, x, x2, M_ROWS, DM, DM);

  ln_kernel<<<M_ROWS, 256, 0, stream>>>(x2, ln2g, ln2b, h2);

  gemm_kernel<2><<<dim3(32, 32), 256, 0, stream>>>(h2, w1T, b1, nullptr, mid,
                                                   M_ROWS, FF, DM);

  gemm_kernel<1><<<dim3(8, 32), 256, 0, stream>>>(mid, w2T, b2, x2, out,
                                                  M_ROWS, DM, FF);
}